// Round 4
// baseline (31.975 us; speedup 1.0000x reference)
//
#include <hip/hip_runtime.h>

// BPS tokenizer: per (batch, basis) argmin_n |pc[b,n]-basis[p]|^2 -> [dist,dx,dy,dz].
// B=16, N=4096, P=4096. 256 blocks (16 b x 16 ptiles of 256 basis) x 1024 threads.
//
// Cloud in LDS as pair-SoA with rotated slots: pair j -> {-2x,-2x',-2y,-2y'}{-2z,-2z',w,w'}.
// argmin key = fma(-2x,bx, fma(-2y,by, fma(-2z,bz, w))) = d2 - |b|^2 (same argmin).
// Q=8 basis/thread: lanes 0-31 and 32-63 cover the SAME 256 basis but different
// 16-pt halves of each 32-pt chunk (2-address broadcast ds_read, free 2-way) ->
// DS instructions per pair halved vs Q=4. v_pk_fma_f32 processes 2 points/instr;
// v_min3 chunk-min (value only); (val, subchunk) tracked lexicographically.
// Halves merged in-wave via shfl_xor(32); waves merged via LDS; winning 16-pt
// subchunk rescanned with the identical fma chain for first-index tie-break.

typedef __attribute__((ext_vector_type(2))) float f32x2;

#define NB 16
#define NN 4096
#define NP 4096
#define PT 256
#define NW 16              // waves per block
#define NQ 8               // basis points per thread
#define THREADS 1024

__device__ __forceinline__ float min3f(float a, float b, float c) {
    float r;
    asm("v_min3_f32 %0, %1, %2, %3" : "=v"(r) : "v"(a), "v"(b), "v"(c));
    return r;
}
__device__ __forceinline__ f32x2 pk_fma(f32x2 a, f32x2 b, f32x2 c) {
    f32x2 d;
    asm("v_pk_fma_f32 %0, %1, %2, %3" : "=v"(d) : "v"(a), "v"(b), "v"(c));
    return d;
}
__device__ __forceinline__ int pslot(int p) {  // rotate pair within its 8-pair group
    return (p & ~7) | (((p & 7) + ((p >> 3) & 7)) & 7);
}

__global__ __launch_bounds__(THREADS, 4) void bps_kernel(
    const float* __restrict__ pc,     // [B, N, 3]
    const float* __restrict__ basis,  // [P, 3]
    float* __restrict__ out)          // [B, P, 4]
{
#pragma clang fp contract(off)
    __shared__ float4 cloudP[NN];            // 64 KB: 2048 pairs x 32B (rotated slots)
    __shared__ float  redv[NW][NQ][32];      // 16 KB
    __shared__ int    redi[NW][NQ][32];      // 16 KB

    const int b     = blockIdx.x >> 4;
    const int ptile = blockIdx.x & 15;
    const int t     = threadIdx.x;
    const int l     = t & 63;
    const int g     = t >> 6;                // wave id 0..15
    const int h     = l >> 5;                // lane half 0/1
    const int pl5   = l & 31;

    // ---- stage 4 points -> 2 rotated pair-SoA slots ----
    {
        const float4* pc4 = (const float4*)(pc + (size_t)b * NN * 3);
        const float4 f0 = pc4[3*t+0], f1 = pc4[3*t+1], f2 = pc4[3*t+2];
        const float X[4] = {f0.x, f0.w, f1.z, f2.y};
        const float Y[4] = {f0.y, f1.x, f1.w, f2.z};
        const float Z[4] = {f0.z, f1.y, f2.x, f2.w};
        float W[4];
        #pragma unroll
        for (int j = 0; j < 4; ++j) W[j] = (X[j]*X[j] + Y[j]*Y[j]) + Z[j]*Z[j];
        #pragma unroll
        for (int pr = 0; pr < 2; ++pr) {
            const int j0 = 2*pr, j1 = 2*pr + 1;
            const int sl = pslot(2*t + pr);
            cloudP[2*sl]   = make_float4(-2.f*X[j0], -2.f*X[j1], -2.f*Y[j0], -2.f*Y[j1]);
            cloudP[2*sl+1] = make_float4(-2.f*Z[j0], -2.f*Z[j1], W[j0], W[j1]);
        }
    }

    // ---- packed basis registers: 8 basis points, p = ptile*256 + 32q + pl5 ----
    const int pbase = (ptile << 8) + pl5;
#define DECLQ(Q) \
    const float bxs##Q = basis[3*(pbase + 32*Q) + 0]; \
    const float bys##Q = basis[3*(pbase + 32*Q) + 1]; \
    const float bzs##Q = basis[3*(pbase + 32*Q) + 2]; \
    const f32x2 bxx##Q = {bxs##Q, bxs##Q}; \
    const f32x2 byy##Q = {bys##Q, bys##Q}; \
    const f32x2 bzz##Q = {bzs##Q, bzs##Q};
    DECLQ(0) DECLQ(1) DECLQ(2) DECLQ(3) DECLQ(4) DECLQ(5) DECLQ(6) DECLQ(7)
#undef DECLQ

    __syncthreads();

    float gm0, gm1, gm2, gm3, gm4, gm5, gm6, gm7;
    gm0 = gm1 = gm2 = gm3 = gm4 = gm5 = gm6 = gm7 = __builtin_inff();
    int cb0 = 0, cb1 = 0, cb2 = 0, cb3 = 0, cb4 = 0, cb5 = 0, cb6 = 0, cb7 = 0;

    for (int c = 0; c < 8; ++c) {
        const int group = (g << 4) + (c << 1) + h;     // subchunk id 0..255, n-order
        const float4* chunk = cloudP + (group << 4);   // 8 pairs = 16 float4
        float cm0, cm1, cm2, cm3, cm4, cm5, cm6, cm7;
        #pragma unroll
        for (int s = 0; s < 8; ++s) {
            const float4 A1 = chunk[2*s];              // 2 addrs/wave (per half)
            const float4 A2 = chunk[2*s+1];
            const f32x2 xs = {A1.x, A1.y};
            const f32x2 ys = {A1.z, A1.w};
            const f32x2 zs = {A2.x, A2.y};
            const f32x2 ws = {A2.z, A2.w};
#define STEPQ(Q) { \
            const f32x2 k = pk_fma(xs, bxx##Q, pk_fma(ys, byy##Q, pk_fma(zs, bzz##Q, ws))); \
            if (s == 0) cm##Q = fminf(k.x, k.y); \
            else        cm##Q = min3f(cm##Q, k.x, k.y); }
            STEPQ(0) STEPQ(1) STEPQ(2) STEPQ(3) STEPQ(4) STEPQ(5) STEPQ(6) STEPQ(7)
#undef STEPQ
        }
#define UPDQ(Q) if (cm##Q < gm##Q) { gm##Q = cm##Q; cb##Q = group; }  // ascending group
        UPDQ(0) UPDQ(1) UPDQ(2) UPDQ(3) UPDQ(4) UPDQ(5) UPDQ(6) UPDQ(7)
#undef UPDQ
    }

    // ---- merge lane halves (same basis, different subchunks) via shfl_xor(32) ----
#define MRGQ(Q) { \
    const float ov = __shfl_xor(gm##Q, 32); \
    const int   oi = __shfl_xor(cb##Q, 32); \
    if (ov < gm##Q || (ov == gm##Q && oi < cb##Q)) { gm##Q = ov; cb##Q = oi; } }
    MRGQ(0) MRGQ(1) MRGQ(2) MRGQ(3) MRGQ(4) MRGQ(5) MRGQ(6) MRGQ(7)
#undef MRGQ

    if (h == 0) {
        redv[g][0][pl5] = gm0; redi[g][0][pl5] = cb0;
        redv[g][1][pl5] = gm1; redi[g][1][pl5] = cb1;
        redv[g][2][pl5] = gm2; redi[g][2][pl5] = cb2;
        redv[g][3][pl5] = gm3; redi[g][3][pl5] = cb3;
        redv[g][4][pl5] = gm4; redi[g][4][pl5] = cb4;
        redv[g][5][pl5] = gm5; redi[g][5][pl5] = cb5;
        redv[g][6][pl5] = gm6; redi[g][6][pl5] = cb6;
        redv[g][7][pl5] = gm7; redi[g][7][pl5] = cb7;
    }

    __syncthreads();

    // ---- reduce 16 waves lexicographically, rescan winning subchunk, emit ----
    if (t < PT) {
        const int q   = t >> 5;
        const int pl2 = t & 31;
        float bm = redv[0][q][pl2];
        int   bC = redi[0][q][pl2];
        #pragma unroll
        for (int gg = 1; gg < NW; ++gg) {
            const float v = redv[gg][q][pl2];
            const int   i = redi[gg][q][pl2];
            if (v < bm || (v == bm && i < bC)) { bm = v; bC = i; }
        }
        const int p  = (ptile << 8) + t;
        const float bx = basis[3*p+0], by = basis[3*p+1], bz = basis[3*p+2];

        const float4* chunk = cloudP + (bC << 4);
        const int rot = bC & 7;
        int found = 0;
        float nx = 0.f, ny = 0.f, nz = 0.f;
        #pragma unroll
        for (int jj = 0; jj < 16; ++jj) {        // true point order for first-index
            const int s = (((jj >> 1) + rot) & 7);
            const float4 A1 = chunk[2*s];
            const float4 A2 = chunk[2*s+1];
            const int hh = jj & 1;
            const float x = hh ? A1.y : A1.x;
            const float y = hh ? A1.w : A1.z;
            const float z = hh ? A2.y : A2.x;
            const float w = hh ? A2.w : A2.z;
            const float key = fmaf(x, bx, fmaf(y, by, fmaf(z, bz, w)));  // identical chain
            if (!found && key == bm) { found = 1; nx = -0.5f*x; ny = -0.5f*y; nz = -0.5f*z; }
        }
        const float dx = nx - bx, dy = ny - by, dz = nz - bz;
        const float dist = sqrtf((dx*dx + dy*dy) + dz*dz);
        ((float4*)out)[(size_t)b * NP + p] = make_float4(dist, dx, dy, dz);
    }
}

extern "C" void kernel_launch(void* const* d_in, const int* in_sizes, int n_in,
                              void* d_out, int out_size, void* d_ws, size_t ws_size,
                              hipStream_t stream) {
    const float* pc    = (const float*)d_in[0];  // [16, 4096, 3]
    const float* basis = (const float*)d_in[1];  // [4096, 3]
    float* out = (float*)d_out;                  // [16, 4096, 4]

    dim3 grid(NB * (NP / PT));  // 256 blocks
    dim3 block(THREADS);
    bps_kernel<<<grid, block, 0, stream>>>(pc, basis, out);
}